// Round 1
// baseline (939.114 us; speedup 1.0000x reference)
//
#include <hip/hip_runtime.h>
#include <hip/hip_bf16.h>

// Problem constants (all powers of two -> index math is shifts/masks)
#define B_   8
#define N_   16384
#define C_   128
#define OUT_ 256
#define E_   262144
// ws word layout: [0, 16777216) = encoded segment-max (B*N*C uints, 64 MB)
//                 [16777216]    = edge-dtype flag (0 = int64, 1 = int32)
#define AMAX_WORDS 16777216u

typedef __attribute__((ext_vector_type(8))) short bf16x8; // 8 bf16 = 4 VGPRs
typedef __attribute__((ext_vector_type(4))) float f32x4;

// Monotonic order-preserving fp32 <-> uint32 encoding; 0 == "empty" (below -inf)
__device__ __forceinline__ unsigned enc_f32(float f) {
  unsigned u = __float_as_uint(f);
  return ((int)u < 0) ? ~u : (u | 0x80000000u);
}
__device__ __forceinline__ float dec_f32(unsigned u) {
  if (u == 0u) return 0.0f; // no incoming edge -> reference fills 0
  unsigned v = (u & 0x80000000u) ? (u & 0x7FFFFFFFu) : ~u;
  return __uint_as_float(v);
}
__device__ __forceinline__ unsigned short f2bf(float f) { // RNE, no NaN inputs
  unsigned u = __float_as_uint(f);
  u += 0x7FFFu + ((u >> 16) & 1u);
  return (unsigned short)(u >> 16);
}
__device__ __forceinline__ float gelu_exact(float v) {
  return 0.5f * v * (1.0f + erff(v * 0.70710678118654752f));
}

// ---------------- kernel 0: zero the max buffer + flag (ws is 0xAA-poisoned) ----
__global__ __launch_bounds__(256) void k_init(unsigned* __restrict__ ws) {
  unsigned i = blockIdx.x * 256u + threadIdx.x; // 4,194,304 uint4 slots
  ((uint4*)ws)[i] = make_uint4(0u, 0u, 0u, 0u);
  if (i == 0u) ws[AMAX_WORDS] = 0u;
}

// ---------------- kernel 1: detect edge dtype (int64 vs int32) ------------------
// Scan the first 524288 32-bit words (safe in both layouts). If int64, odd words
// are high halves of row indices in [0,16384) -> all zero. If int32, odd words
// are random row values -> some nonzero.
__global__ __launch_bounds__(256) void k_detect(const unsigned* __restrict__ eidx,
                                                unsigned* __restrict__ flag) {
  unsigned i = blockIdx.x * 256u + threadIdx.x; // 0..262143
  unsigned w = eidx[2u * i + 1u];
  if (__any((int)(w != 0u)) && (threadIdx.x & 63u) == 0u) atomicOr(flag, 1u);
}

// ---------------- kernel 2: scatter-max over edges ------------------------------
// One thread per (edge, channel); loops all 8 batches (edge read amortized).
__global__ __launch_bounds__(256) void k_scatter(const float* __restrict__ x,
                                                 const void* __restrict__ eidx,
                                                 unsigned* __restrict__ ws) {
  unsigned g = blockIdx.x * 256u + threadIdx.x; // 0 .. E*C-1 (2^25)
  unsigned c = g & 127u;
  unsigned e = g >> 7;
  int row, col;
  if (ws[AMAX_WORDS] == 0u) { // int64 edges (wave-uniform branch)
    const long long* p = (const long long*)eidx;
    row = (int)p[e];
    col = (int)p[e + E_];
  } else {                    // int32 edges
    const int* p = (const int*)eidx;
    row = p[e];
    col = p[e + E_];
  }
  unsigned src = ((unsigned)col << 7) + c;
  unsigned dst = ((unsigned)row << 7) + c;
#pragma unroll
  for (unsigned b = 0; b < 8u; ++b) {
    float v = x[(b << 21) + src];
    atomicMax(ws + (b << 21) + dst, enc_f32(v));
  }
}

// ---------------- kernel 3: fused (decode - x) @ W + b, exact GELU --------------
// Tile: 64 rows (4 waves x 16) x 128 cols per block; K=128 fully in LDS.
// LDS rows padded +8 bf16 (stride 136 -> 2-way bank aliasing, which is free).
__global__ __launch_bounds__(256, 3) void k_gemm(const unsigned* __restrict__ amax,
                                                 const float* __restrict__ x,
                                                 const float* __restrict__ W,
                                                 const float* __restrict__ bias,
                                                 float* __restrict__ out) {
  __shared__ unsigned short A_sm[64 * 136];   // 17408 B
  __shared__ unsigned short Wt_sm[128 * 136]; // 34816 B (W transposed: [n][k])
  const int tid = threadIdx.x;
  const int mbase = blockIdx.x * 64;
  const int nbase = blockIdx.y * 128;

  // Stage A tile: aggr = dec(amax) - x, cast bf16. 64x128 = 2048 float4 slots.
#pragma unroll
  for (int i = 0; i < 8; ++i) {
    int slot = i * 256 + tid;
    int r = slot >> 5;
    int c4 = slot & 31;
    size_t off = (size_t)(mbase + r) * 128 + (size_t)(c4 * 4);
    uint4 u = *(const uint4*)(amax + off);
    float4 xv = *(const float4*)(x + off);
    ushort4 h;
    h.x = f2bf(dec_f32(u.x) - xv.x);
    h.y = f2bf(dec_f32(u.y) - xv.y);
    h.z = f2bf(dec_f32(u.z) - xv.z);
    h.w = f2bf(dec_f32(u.w) - xv.w);
    *(ushort4*)&A_sm[r * 136 + c4 * 4] = h;
  }
  // Stage W^T tile in bf16: Wt[n][k] so B-fragment loads are contiguous 16B.
#pragma unroll
  for (int i = 0; i < 64; ++i) {
    int slot = i * 256 + tid;
    int k = slot >> 7;
    int nl = slot & 127;
    Wt_sm[nl * 136 + k] = f2bf(W[k * 256 + nbase + nl]);
  }
  __syncthreads();

  const int lane = tid & 63;
  const int wv = tid >> 6;   // wave id: rows [wv*16, wv*16+16)
  const int ln = lane & 15;
  const int q = lane >> 4;   // quad

  f32x4 acc[8];
#pragma unroll
  for (int f = 0; f < 8; ++f) acc[f] = (f32x4){0.f, 0.f, 0.f, 0.f};

#pragma unroll
  for (int kc = 0; kc < 4; ++kc) {
    // A-operand layout: A[m = lane&15][k = quad*8 + j]  (m120-verified)
    bf16x8 af = *(const bf16x8*)&A_sm[(wv * 16 + ln) * 136 + kc * 32 + q * 8];
#pragma unroll
    for (int f = 0; f < 8; ++f) {
      // B-operand: B[k = quad*8 + j][n = lane&15] -> contiguous in Wt[n][k]
      bf16x8 bf = *(const bf16x8*)&Wt_sm[(f * 16 + ln) * 136 + kc * 32 + q * 8];
      acc[f] = __builtin_amdgcn_mfma_f32_16x16x32_bf16(af, bf, acc[f], 0, 0, 0);
    }
  }

  // Epilogue: C/D layout col = lane&15, row = quad*4 + reg (m89-verified)
#pragma unroll
  for (int f = 0; f < 8; ++f) {
    int n = nbase + f * 16 + ln;
    float bv = bias[n];
#pragma unroll
    for (int r = 0; r < 4; ++r) {
      int m = mbase + wv * 16 + q * 4 + r;
      out[(size_t)m * 256 + n] = gelu_exact(acc[f][r] + bv);
    }
  }
}

extern "C" void kernel_launch(void* const* d_in, const int* in_sizes, int n_in,
                              void* d_out, int out_size, void* d_ws, size_t ws_size,
                              hipStream_t stream) {
  const float* x   = (const float*)d_in[0];
  const void* eidx = d_in[1];
  const float* W   = (const float*)d_in[2];
  const float* bia = (const float*)d_in[3];
  float* out       = (float*)d_out;
  unsigned* ws     = (unsigned*)d_ws;

  hipLaunchKernelGGL(k_init,    dim3(16384),   dim3(256), 0, stream, ws);
  hipLaunchKernelGGL(k_detect,  dim3(1024),    dim3(256), 0, stream,
                     (const unsigned*)eidx, ws + AMAX_WORDS);
  hipLaunchKernelGGL(k_scatter, dim3(131072),  dim3(256), 0, stream, x, eidx, ws);
  hipLaunchKernelGGL(k_gemm,    dim3(2048, 2), dim3(256), 0, stream, ws, x, W, bia, out);
}

// Round 2
// 461.526 us; speedup vs baseline: 2.0348x; 2.0348x over previous
//
#include <hip/hip_runtime.h>
#include <hip/hip_bf16.h>

// Problem constants (all powers of two -> index math is shifts/masks)
#define B_   8
#define N_   16384
#define C_   128
#define OUT_ 256
#define E_   262144

// ws word layout (uint32 offsets):
//   [0]                : edge-dtype flag (0 = int64, 1 = int32)
//   [64,      16448)   : deg -> (after scan) build cursors            (16384)
//   [16448,   32833)   : offs exclusive prefix, offs[16384] = E       (16385)
//   [32896,   295040)  : sorted_col (counting-sorted by row)          (262144)
//   [295040,  311424)  : Wt bf16, [n][k] transposed weights           (16384)
//   [311424,  8700032) : aggr bf16, (max_j x_j - x_i), B*N*C shorts   (8388608)
#define FLAG_OFF 0u
#define DEG_OFF  64u
#define OFFS_OFF 16448u
#define SCOL_OFF 32896u
#define WT_OFF   295040u
#define AGGR_OFF 311424u

typedef __attribute__((ext_vector_type(8))) short bf16x8; // 8 bf16 = 4 VGPRs
typedef __attribute__((ext_vector_type(4))) float f32x4;

__device__ __forceinline__ unsigned short f2bf(float f) { // RNE, no NaN inputs
  unsigned u = __float_as_uint(f);
  u += 0x7FFFu + ((u >> 16) & 1u);
  return (unsigned short)(u >> 16);
}
__device__ __forceinline__ float gelu_exact(float v) {
  return 0.5f * v * (1.0f + erff(v * 0.70710678118654752f));
}

// ---------------- kernel 0: zero flag + deg histogram ---------------------------
__global__ __launch_bounds__(256) void k_init(unsigned* __restrict__ ws) {
  unsigned i = blockIdx.x * 256u + threadIdx.x; // 65*256 = 16640 >= 16448
  ws[i] = 0u; // spill past 16448 lands in offs[], fully rewritten by k_scan
}

// ---------------- kernel 1: detect edge dtype (int64 vs int32) ------------------
// Odd 32-bit words of the first E entries: int64 -> high halves of rows (<16384,
// all zero); int32 -> random row values (some nonzero).
__global__ __launch_bounds__(256) void k_detect(const unsigned* __restrict__ eidx,
                                                unsigned* __restrict__ flag) {
  unsigned i = blockIdx.x * 256u + threadIdx.x; // 0..262143
  unsigned w = eidx[2u * i + 1u];
  if (__any((int)(w != 0u)) && (threadIdx.x & 63u) == 0u) atomicOr(flag, 1u);
}

__device__ __forceinline__ void load_edge(const void* eidx, unsigned e,
                                          unsigned flag, int& row, int& col) {
  if (flag == 0u) {
    const long long* p = (const long long*)eidx;
    row = (int)p[e];
    col = (int)p[e + E_];
  } else {
    const int* p = (const int*)eidx;
    row = p[e];
    col = p[e + E_];
  }
}

// ---------------- kernel 2: degree histogram ------------------------------------
__global__ __launch_bounds__(256) void k_hist(const void* __restrict__ eidx,
                                              unsigned* __restrict__ ws) {
  unsigned e = blockIdx.x * 256u + threadIdx.x;
  int row, col;
  load_edge(eidx, e, ws[FLAG_OFF], row, col);
  atomicAdd(ws + DEG_OFF + row, 1u);
}

// ---------------- kernel 3: exclusive scan (single block) -----------------------
__global__ __launch_bounds__(1024) void k_scan(unsigned* __restrict__ ws) {
  __shared__ unsigned part[1024];
  const unsigned t = threadIdx.x;
  unsigned* deg  = ws + DEG_OFF;
  unsigned* offs = ws + OFFS_OFF;
  unsigned v[16], s = 0;
#pragma unroll
  for (int j = 0; j < 16; ++j) { v[j] = deg[t * 16 + j]; s += v[j]; }
  part[t] = s;
  __syncthreads();
  for (int d = 1; d < 1024; d <<= 1) {
    unsigned add = (t >= (unsigned)d) ? part[t - d] : 0u;
    __syncthreads();
    part[t] += add;
    __syncthreads();
  }
  unsigned base = (t == 0u) ? 0u : part[t - 1];
#pragma unroll
  for (int j = 0; j < 16; ++j) {
    unsigned pv = v[j];
    offs[t * 16 + j] = base;
    deg[t * 16 + j] = base; // deg[] becomes the build cursor
    base += pv;
  }
  if (t == 1023u) offs[16384] = base; // == E
}

// ---------------- kernel 4: counting-sort edges by row --------------------------
__global__ __launch_bounds__(256) void k_build(const void* __restrict__ eidx,
                                               unsigned* __restrict__ ws) {
  unsigned e = blockIdx.x * 256u + threadIdx.x;
  int row, col;
  load_edge(eidx, e, ws[FLAG_OFF], row, col);
  unsigned pos = atomicAdd(ws + DEG_OFF + row, 1u);
  ws[SCOL_OFF + pos] = (unsigned)col;
}

// ---------------- kernel 5: W fp32 -> bf16 transposed ---------------------------
__global__ __launch_bounds__(256) void k_wprep(const float* __restrict__ W,
                                               unsigned short* __restrict__ Wt) {
  unsigned t = blockIdx.x * 256u + threadIdx.x; // 32768
  unsigned n = t >> 7, k = t & 127u;
  Wt[n * 128u + k] = f2bf(W[k * 256u + n]);
}

// ---------------- kernel 6: CSR gather-max, write aggr = max - x in bf16 --------
// Block = 2 rows x 128 channels; batch is the slowest grid dim so the active
// x-slice (~8 MB) stays L2-warm.
__global__ __launch_bounds__(256) void k_aggr(const float* __restrict__ x,
                                              const unsigned* __restrict__ ws,
                                              unsigned short* __restrict__ aggr) {
  const unsigned bi  = blockIdx.x;                     // 65536
  const unsigned b   = bi >> 13;
  const unsigned row = ((bi & 8191u) << 1) | (threadIdx.x >> 7);
  const unsigned c   = threadIdx.x & 127u;
  const unsigned* offs = ws + OFFS_OFF;
  const unsigned* scol = ws + SCOL_OFF;
  const float* xb = x + ((size_t)b << 21);

  unsigned j = offs[row], s1 = offs[row + 1];
  const bool has = (j < s1);
  float m = -INFINITY;
  for (; j + 4 <= s1; j += 4) { // 4-wide for load ILP (scol is wave-uniform)
    unsigned c0 = scol[j], c1 = scol[j + 1], c2 = scol[j + 2], c3 = scol[j + 3];
    float v0 = xb[(c0 << 7) + c], v1 = xb[(c1 << 7) + c];
    float v2 = xb[(c2 << 7) + c], v3 = xb[(c3 << 7) + c];
    m = fmaxf(m, fmaxf(fmaxf(v0, v1), fmaxf(v2, v3)));
  }
  for (; j < s1; ++j) m = fmaxf(m, xb[(scol[j] << 7) + c]);

  float xr = xb[(row << 7) + c];
  aggr[((size_t)b << 21) + (row << 7) + c] = f2bf((has ? m : 0.0f) - xr);
}

// ---------------- kernel 7: aggr(bf16) @ Wt(bf16) + b, exact GELU ---------------
// Tile: 64 rows (4 waves x 16) x 128 cols; K=128 in LDS; stride 136 (2-way free).
__global__ __launch_bounds__(256, 3) void k_gemm(const unsigned short* __restrict__ aggr,
                                                 const unsigned short* __restrict__ Wt,
                                                 const float* __restrict__ bias,
                                                 float* __restrict__ out) {
  __shared__ unsigned short A_sm[64 * 136];   // 17408 B
  __shared__ unsigned short Wt_sm[128 * 136]; // 34816 B
  const int tid = threadIdx.x;
  const int mbase = blockIdx.x * 64;
  const int nbase = blockIdx.y * 128;

  // Stage A: 64 rows x 128 bf16 = 1024 uint4 slots (16B per slot, 16 per row)
#pragma unroll
  for (int i = 0; i < 4; ++i) {
    int slot = i * 256 + tid;
    int r = slot >> 4, c8 = slot & 15;
    uint4 u = *(const uint4*)(aggr + (size_t)(mbase + r) * 128 + c8 * 8);
    *(uint4*)&A_sm[r * 136 + c8 * 8] = u; // 272B row stride: 16B-aligned
  }
  // Stage Wt: 128 n-rows x 128 bf16 = 2048 uint4 slots
#pragma unroll
  for (int i = 0; i < 8; ++i) {
    int slot = i * 256 + tid;
    int n = slot >> 4, k8 = slot & 15;
    uint4 u = *(const uint4*)(Wt + (size_t)(nbase + n) * 128 + k8 * 8);
    *(uint4*)&Wt_sm[n * 136 + k8 * 8] = u;
  }
  __syncthreads();

  const int lane = tid & 63;
  const int wv = tid >> 6;   // wave id: rows [wv*16, wv*16+16)
  const int ln = lane & 15;
  const int q = lane >> 4;   // quad

  f32x4 acc[8];
#pragma unroll
  for (int f = 0; f < 8; ++f) acc[f] = (f32x4){0.f, 0.f, 0.f, 0.f};

#pragma unroll
  for (int kc = 0; kc < 4; ++kc) {
    // A-operand: A[m = lane&15][k = quad*8 + j]
    bf16x8 af = *(const bf16x8*)&A_sm[(wv * 16 + ln) * 136 + kc * 32 + q * 8];
#pragma unroll
    for (int f = 0; f < 8; ++f) {
      // B-operand: B[k = quad*8 + j][n = lane&15] contiguous in Wt[n][k]
      bf16x8 bf = *(const bf16x8*)&Wt_sm[(f * 16 + ln) * 136 + kc * 32 + q * 8];
      acc[f] = __builtin_amdgcn_mfma_f32_16x16x32_bf16(af, bf, acc[f], 0, 0, 0);
    }
  }

  // Epilogue: C/D layout col = lane&15, row = quad*4 + reg (m89-verified)
#pragma unroll
  for (int f = 0; f < 8; ++f) {
    int n = nbase + f * 16 + ln;
    float bv = bias[n];
#pragma unroll
    for (int r = 0; r < 4; ++r) {
      int m = mbase + wv * 16 + q * 4 + r;
      out[(size_t)m * 256 + n] = gelu_exact(acc[f][r] + bv);
    }
  }
}

extern "C" void kernel_launch(void* const* d_in, const int* in_sizes, int n_in,
                              void* d_out, int out_size, void* d_ws, size_t ws_size,
                              hipStream_t stream) {
  const float* x   = (const float*)d_in[0];
  const void* eidx = d_in[1];
  const float* W   = (const float*)d_in[2];
  const float* bia = (const float*)d_in[3];
  float* out       = (float*)d_out;
  unsigned* ws     = (unsigned*)d_ws;

  unsigned short* Wt   = (unsigned short*)(ws + WT_OFF);
  unsigned short* aggr = (unsigned short*)(ws + AGGR_OFF);

  hipLaunchKernelGGL(k_init,   dim3(65),      dim3(256),  0, stream, ws);
  hipLaunchKernelGGL(k_detect, dim3(1024),    dim3(256),  0, stream,
                     (const unsigned*)eidx, ws + FLAG_OFF);
  hipLaunchKernelGGL(k_hist,   dim3(1024),    dim3(256),  0, stream, eidx, ws);
  hipLaunchKernelGGL(k_scan,   dim3(1),       dim3(1024), 0, stream, ws);
  hipLaunchKernelGGL(k_build,  dim3(1024),    dim3(256),  0, stream, eidx, ws);
  hipLaunchKernelGGL(k_wprep,  dim3(128),     dim3(256),  0, stream, W, Wt);
  hipLaunchKernelGGL(k_aggr,   dim3(65536),   dim3(256),  0, stream, x, ws, aggr);
  hipLaunchKernelGGL(k_gemm,   dim3(2048, 2), dim3(256),  0, stream, aggr, Wt, bia, out);
}

// Round 4
// 388.172 us; speedup vs baseline: 2.4193x; 1.1890x over previous
//
#include <hip/hip_runtime.h>
#include <hip/hip_bf16.h>

// Problem constants (all powers of two -> index math is shifts/masks)
#define B_   8
#define N_   16384
#define C_   128
#define OUT_ 256
#define E_   262144

// ws word layout (uint32 offsets):
//   [0]                 : edge-dtype flag (0 = int64, 1 = int32)
//   [64,      16448)    : deg -> (after scan) build cursors            (16384)
//   [16448,   32833)    : offs exclusive prefix, offs[16384] = E       (16385)
//   [32896,   295040)   : sorted_col (counting-sorted by row)          (262144)
//   [295040,  311424)   : Wt bf16, [n][k] transposed weights           (16384 u32!)
//   [311424,  8700032)  : x_bf bf16 copy of x (B*N*C shorts)           (8388608 u32)
//   [8700032, 17088640) : aggr bf16 (max_j x_j - x_i)                  (8388608 u32)
// Fallback (ws too small): aggr lives at 311424 instead; no x_bf.
#define FLAG_OFF 0u
#define DEG_OFF  64u
#define OFFS_OFF 16448u
#define SCOL_OFF 32896u
#define WT_OFF   295040u
#define XBF_OFF  311424u
#define AGGR_OFF 8700032u
#define WS_NEED_BYTES ((size_t)(AGGR_OFF + 8388608u) * 4u)

typedef __attribute__((ext_vector_type(8))) short bf16x8; // 8 bf16 = 4 VGPRs
typedef __attribute__((ext_vector_type(4))) float f32x4;

__device__ __forceinline__ unsigned short f2bf(float f) { // RNE, no NaN inputs
  unsigned u = __float_as_uint(f);
  u += 0x7FFFu + ((u >> 16) & 1u);
  return (unsigned short)(u >> 16);
}
__device__ __forceinline__ float gelu_exact(float v) {
  return 0.5f * v * (1.0f + erff(v * 0.70710678118654752f));
}

// ---------------- kernel 0: zero flag+deg AND W fp32->bf16 transposed -----------
// 128 blocks x 256 threads. Disjoint writes, no ordering hazard.
__global__ __launch_bounds__(256) void k_prep0(const float* __restrict__ W,
                                               unsigned* __restrict__ ws) {
  unsigned t = blockIdx.x * 256u + threadIdx.x; // 0..32767
  unsigned n = t >> 7, k = t & 127u;
  ((unsigned short*)(ws + WT_OFF))[n * 128u + k] = f2bf(W[k * 256u + n]);
  if (t < 16640u) ws[t] = 0u; // flag + deg (spill into offs, rewritten by scan)
}

// ---------------- kernel 1: detect edge dtype (int64 vs int32) ------------------
// Odd 32-bit words: int64 -> high halves of indices (<16384, all zero);
// int32 -> random index values (some nonzero).
__global__ __launch_bounds__(256) void k_detect(const unsigned* __restrict__ eidx,
                                                unsigned* __restrict__ flag) {
  unsigned i = blockIdx.x * 256u + threadIdx.x; // 0..262143
  unsigned w = eidx[2u * i + 1u];
  if (__any((int)(w != 0u)) && (threadIdx.x & 63u) == 0u) atomicOr(flag, 1u);
}

__device__ __forceinline__ void load_edge(const void* eidx, unsigned e,
                                          unsigned flag, int& row, int& col) {
  if (flag == 0u) {
    const long long* p = (const long long*)eidx;
    row = (int)p[e];
    col = (int)p[e + E_];
  } else {
    const int* p = (const int*)eidx;
    row = p[e];
    col = p[e + E_];
  }
}

// ---------------- kernel 2: degree histogram ------------------------------------
__global__ __launch_bounds__(256) void k_hist(const void* __restrict__ eidx,
                                              unsigned* __restrict__ ws) {
  unsigned e = blockIdx.x * 256u + threadIdx.x;
  int row, col;
  load_edge(eidx, e, ws[FLAG_OFF], row, col);
  atomicAdd(ws + DEG_OFF + row, 1u);
}

// ---------------- kernel 3: exclusive scan (single block) -----------------------
__global__ __launch_bounds__(1024) void k_scan(unsigned* __restrict__ ws) {
  __shared__ unsigned part[1024];
  const unsigned t = threadIdx.x;
  unsigned* deg  = ws + DEG_OFF;
  unsigned* offs = ws + OFFS_OFF;
  unsigned v[16], s = 0;
#pragma unroll
  for (int j = 0; j < 16; ++j) { v[j] = deg[t * 16 + j]; s += v[j]; }
  part[t] = s;
  __syncthreads();
  for (int d = 1; d < 1024; d <<= 1) {
    unsigned add = (t >= (unsigned)d) ? part[t - d] : 0u;
    __syncthreads();
    part[t] += add;
    __syncthreads();
  }
  unsigned base = (t == 0u) ? 0u : part[t - 1];
#pragma unroll
  for (int j = 0; j < 16; ++j) {
    unsigned pv = v[j];
    offs[t * 16 + j] = base;
    deg[t * 16 + j] = base; // deg[] becomes the build cursor
    base += pv;
  }
  if (t == 1023u) offs[16384] = base; // == E
}

// ---------------- kernel 4: counting-sort edges by row --------------------------
__global__ __launch_bounds__(256) void k_build(const void* __restrict__ eidx,
                                               unsigned* __restrict__ ws) {
  unsigned e = blockIdx.x * 256u + threadIdx.x;
  int row, col;
  load_edge(eidx, e, ws[FLAG_OFF], row, col);
  unsigned pos = atomicAdd(ws + DEG_OFF + row, 1u);
  ws[SCOL_OFF + pos] = (unsigned)col;
}

// ---------------- kernel 5: x fp32 -> bf16 packed -------------------------------
__global__ __launch_bounds__(256) void k_xbf(const float* __restrict__ x,
                                             unsigned* __restrict__ xbf) {
  unsigned i = blockIdx.x * 256u + threadIdx.x; // 0..4194303, float4 slots
  float4 v = ((const float4*)x)[i];
  uint2 o;
  o.x = (unsigned)f2bf(v.x) | ((unsigned)f2bf(v.y) << 16);
  o.y = (unsigned)f2bf(v.z) | ((unsigned)f2bf(v.w) << 16);
  ((uint2*)xbf)[i] = o;
}

// ---------------- kernel 6: CSR gather-max on bf16, XCD-batch affinity ----------
// b = blockIdx&7 -> (heuristic) each XCD mostly touches one 4 MB batch slice,
// which fits its L2. Gather unit = u32 (2 bf16 channels). Max trick: fmax on raw
// u32 (hi channel; garbage low mantissa can't flip a bf16-level compare) and on
// u<<16 (lo channel, exact). Winner's hi16 is the exact bf16 max.
__global__ __launch_bounds__(256) void k_aggr2(const unsigned* __restrict__ xbf,
                                               const unsigned* __restrict__ ws,
                                               unsigned* __restrict__ aggr32) {
  const unsigned bi = blockIdx.x;                 // 32768 = 8 batches x 4096 rowgrps
  const unsigned b  = bi & 7u;
  const unsigned row = ((bi >> 3) << 2) | (threadIdx.x >> 6); // wave <-> row
  const unsigned ln = threadIdx.x & 63u;          // channel-pair
  const unsigned* offs = ws + OFFS_OFF;
  const unsigned* scol = ws + SCOL_OFF;
  const unsigned* xb = xbf + ((size_t)b << 20);   // N*C/2 u32 per batch

  unsigned j = offs[row], e1 = offs[row + 1];
  const bool has = (j < e1);
  float mlo = -INFINITY, mhi = -INFINITY;
  while (j + 8u <= e1) {
    unsigned uw[8];
#pragma unroll
    for (int t = 0; t < 8; ++t) {
      unsigned col = (unsigned)__builtin_amdgcn_readfirstlane(scol[j + t]);
      uw[t] = xb[(col << 6) + ln];
    }
#pragma unroll
    for (int t = 0; t < 8; ++t) {
      mlo = fmaxf(mlo, __uint_as_float(uw[t] << 16));
      mhi = fmaxf(mhi, __uint_as_float(uw[t]));
    }
    j += 8u;
  }
  for (; j < e1; ++j) {
    unsigned col = (unsigned)__builtin_amdgcn_readfirstlane(scol[j]);
    unsigned u = xb[(col << 6) + ln];
    mlo = fmaxf(mlo, __uint_as_float(u << 16));
    mhi = fmaxf(mhi, __uint_as_float(u));
  }
  float Mlo = has ? mlo : 0.0f;
  float Mhi = has ? __uint_as_float(__float_as_uint(mhi) & 0xFFFF0000u) : 0.0f;
  unsigned xw = xb[(row << 6) + ln];
  float xlo = __uint_as_float(xw << 16);
  float xhi = __uint_as_float(xw & 0xFFFF0000u);
  unsigned lo = f2bf(Mlo - xlo);
  unsigned hi = f2bf(Mhi - xhi);
  aggr32[((size_t)b << 20) + (row << 6) + ln] = lo | (hi << 16);
}

// ---------------- kernel 6-fallback: fp32 gather (small ws), +affinity ----------
__global__ __launch_bounds__(256) void k_aggr(const float* __restrict__ x,
                                              const unsigned* __restrict__ ws,
                                              unsigned short* __restrict__ aggr) {
  const unsigned bi  = blockIdx.x;                // 65536
  const unsigned b   = bi & 7u;
  const unsigned row = ((bi >> 3) << 1) | (threadIdx.x >> 7);
  const unsigned c   = threadIdx.x & 127u;
  const unsigned* offs = ws + OFFS_OFF;
  const unsigned* scol = ws + SCOL_OFF;
  const float* xb = x + ((size_t)b << 21);

  unsigned j = offs[row], s1 = offs[row + 1];
  const bool has = (j < s1);
  float m = -INFINITY;
  for (; j + 4 <= s1; j += 4) {
    unsigned c0 = scol[j], c1 = scol[j + 1], c2 = scol[j + 2], c3 = scol[j + 3];
    float v0 = xb[(c0 << 7) + c], v1 = xb[(c1 << 7) + c];
    float v2 = xb[(c2 << 7) + c], v3 = xb[(c3 << 7) + c];
    m = fmaxf(m, fmaxf(fmaxf(v0, v1), fmaxf(v2, v3)));
  }
  for (; j < s1; ++j) m = fmaxf(m, xb[(scol[j] << 7) + c]);

  float xr = xb[(row << 7) + c];
  aggr[((size_t)b << 21) + (row << 7) + c] = f2bf((has ? m : 0.0f) - xr);
}

// ---------------- kernel 7: aggr(bf16) @ Wt(bf16) + b, exact GELU ---------------
__global__ __launch_bounds__(256, 3) void k_gemm(const unsigned short* __restrict__ aggr,
                                                 const unsigned short* __restrict__ Wt,
                                                 const float* __restrict__ bias,
                                                 float* __restrict__ out) {
  __shared__ unsigned short A_sm[64 * 136];   // 17408 B
  __shared__ unsigned short Wt_sm[128 * 136]; // 34816 B
  const int tid = threadIdx.x;
  const int mbase = blockIdx.x * 64;
  const int nbase = blockIdx.y * 128;

#pragma unroll
  for (int i = 0; i < 4; ++i) {
    int slot = i * 256 + tid;
    int r = slot >> 4, c8 = slot & 15;
    uint4 u = *(const uint4*)(aggr + (size_t)(mbase + r) * 128 + c8 * 8);
    *(uint4*)&A_sm[r * 136 + c8 * 8] = u;
  }
#pragma unroll
  for (int i = 0; i < 8; ++i) {
    int slot = i * 256 + tid;
    int n = slot >> 4, k8 = slot & 15;
    uint4 u = *(const uint4*)(Wt + (size_t)(nbase + n) * 128 + k8 * 8);
    *(uint4*)&Wt_sm[n * 136 + k8 * 8] = u;
  }
  __syncthreads();

  const int lane = tid & 63;
  const int wv = tid >> 6;
  const int ln = lane & 15;
  const int q = lane >> 4;

  f32x4 acc[8];
#pragma unroll
  for (int f = 0; f < 8; ++f) acc[f] = (f32x4){0.f, 0.f, 0.f, 0.f};

#pragma unroll
  for (int kc = 0; kc < 4; ++kc) {
    bf16x8 af = *(const bf16x8*)&A_sm[(wv * 16 + ln) * 136 + kc * 32 + q * 8];
#pragma unroll
    for (int f = 0; f < 8; ++f) {
      bf16x8 bf = *(const bf16x8*)&Wt_sm[(f * 16 + ln) * 136 + kc * 32 + q * 8];
      acc[f] = __builtin_amdgcn_mfma_f32_16x16x32_bf16(af, bf, acc[f], 0, 0, 0);
    }
  }

#pragma unroll
  for (int f = 0; f < 8; ++f) {
    int n = nbase + f * 16 + ln;
    float bv = bias[n];
#pragma unroll
    for (int r = 0; r < 4; ++r) {
      int m = mbase + wv * 16 + q * 4 + r;
      out[(size_t)m * 256 + n] = gelu_exact(acc[f][r] + bv);
    }
  }
}

extern "C" void kernel_launch(void* const* d_in, const int* in_sizes, int n_in,
                              void* d_out, int out_size, void* d_ws, size_t ws_size,
                              hipStream_t stream) {
  const float* x   = (const float*)d_in[0];
  const void* eidx = d_in[1];
  const float* W   = (const float*)d_in[2];
  const float* bia = (const float*)d_in[3];
  float* out       = (float*)d_out;
  unsigned* ws     = (unsigned*)d_ws;

  const bool big = (ws_size >= WS_NEED_BYTES); // constant per run -> graph-safe
  unsigned short* Wt   = (unsigned short*)(ws + WT_OFF);
  unsigned* aggr32     = ws + (big ? AGGR_OFF : XBF_OFF);
  unsigned short* aggr = (unsigned short*)aggr32;

  hipLaunchKernelGGL(k_prep0,  dim3(128),     dim3(256),  0, stream, W, ws);
  hipLaunchKernelGGL(k_detect, dim3(1024),    dim3(256),  0, stream,
                     (const unsigned*)eidx, ws + FLAG_OFF);
  hipLaunchKernelGGL(k_hist,   dim3(1024),    dim3(256),  0, stream, eidx, ws);
  hipLaunchKernelGGL(k_scan,   dim3(1),       dim3(1024), 0, stream, ws);
  hipLaunchKernelGGL(k_build,  dim3(1024),    dim3(256),  0, stream, eidx, ws);
  if (big) {
    hipLaunchKernelGGL(k_xbf,   dim3(16384), dim3(256), 0, stream, x, ws + XBF_OFF);
    hipLaunchKernelGGL(k_aggr2, dim3(32768), dim3(256), 0, stream,
                       ws + XBF_OFF, ws, aggr32);
  } else {
    hipLaunchKernelGGL(k_aggr,  dim3(65536), dim3(256), 0, stream, x, ws, aggr);
  }
  hipLaunchKernelGGL(k_gemm,   dim3(2048, 2), dim3(256), 0, stream, aggr, Wt, bia, out);
}

// Round 5
// 334.598 us; speedup vs baseline: 2.8067x; 1.1601x over previous
//
#include <hip/hip_runtime.h>
#include <hip/hip_bf16.h>

// Problem constants (all powers of two -> index math is shifts/masks)
#define B_   8
#define N_   16384
#define C_   128
#define OUT_ 256
#define E_   262144

// ws word layout (uint32 offsets). ws_size measured ~537 MB (round-4 fill
// counters), we need 68.4 MB.
//   [0,       16384)    : deg; memset 0 -> hist; scan rewrites as build cursors
//   [16384,   32769)    : offs exclusive prefix, offs[16384] = E
//   [32832,   294976)   : sorted_col (counting-sorted by row)
//   [294976,  311360)   : Wt bf16 [n][k] transposed weights (256x128)
//   [311360,  8699968)  : x_bf bf16 copy of x (B*N*C shorts)
//   [8699968, 17088576) : aggr bf16 (max_j x_j - x_i), row-major (b,row,c)
#define DEG_OFF  0u
#define OFFS_OFF 16384u
#define SCOL_OFF 32832u
#define WT_OFF   294976u
#define XBF_OFF  311360u
#define AGGR_OFF 8699968u

typedef __attribute__((ext_vector_type(8))) short bf16x8; // 8 bf16 = 4 VGPRs
typedef __attribute__((ext_vector_type(4))) float f32x4;

__device__ __forceinline__ unsigned short f2bf(float f) { // RNE, no NaN inputs
  unsigned u = __float_as_uint(f);
  u += 0x7FFFu + ((u >> 16) & 1u);
  return (unsigned short)(u >> 16);
}
__device__ __forceinline__ float gelu_exact(float v) {
  return 0.5f * v * (1.0f + erff(v * 0.70710678118654752f));
}

// ---------------- kernel 1: fused x->bf16 | deg histogram | Wt prep -------------
// Per-block dtype detect: odd u32 words are int64-highs (==0) or int32 index
// values (nonzero w.h.p.); 256 samples/block -> P(wrong) = 16384^-256 ~ 0.
__global__ __launch_bounds__(256) void k_fused1(const float* __restrict__ x,
                                                const unsigned* __restrict__ eidx,
                                                const float* __restrict__ W,
                                                unsigned* __restrict__ ws) {
  const unsigned bid = blockIdx.x, tid = threadIdx.x;
  if (bid < 16384u) { // ---- x fp32 -> bf16 packed (4,194,304 float4 slots)
    unsigned i = bid * 256u + tid;
    float4 v = ((const float4*)x)[i];
    uint2 o;
    o.x = (unsigned)f2bf(v.x) | ((unsigned)f2bf(v.y) << 16);
    o.y = (unsigned)f2bf(v.z) | ((unsigned)f2bf(v.w) << 16);
    ((uint2*)(ws + XBF_OFF))[i] = o;
  } else if (bid < 17408u) { // ---- degree histogram, one edge per thread
    __shared__ int flag32;
    if (tid == 0) flag32 = 0;
    __syncthreads();
    unsigned e = (bid - 16384u) * 256u + tid; // 0..262143
    if (eidx[2u * e + 1u] != 0u) flag32 = 1;  // benign race
    __syncthreads();
    int row = flag32 ? (int)eidx[e] : (int)((const long long*)eidx)[e];
    atomicAdd(ws + DEG_OFF + (unsigned)row, 1u);
  } else { // ---- W fp32 -> bf16 transposed (128 blocks)
    unsigned t = (bid - 17408u) * 256u + tid; // 0..32767
    unsigned n = t >> 7, k = t & 127u;
    ((unsigned short*)(ws + WT_OFF))[n * 128u + k] = f2bf(W[k * 256u + n]);
  }
}

// ---------------- kernel 2: exclusive scan (single block) -----------------------
__global__ __launch_bounds__(1024) void k_scan(unsigned* __restrict__ ws) {
  __shared__ unsigned part[1024];
  const unsigned t = threadIdx.x;
  unsigned* deg  = ws + DEG_OFF;
  unsigned* offs = ws + OFFS_OFF;
  unsigned v[16], s = 0;
#pragma unroll
  for (int j = 0; j < 16; ++j) { v[j] = deg[t * 16 + j]; s += v[j]; }
  part[t] = s;
  __syncthreads();
  for (int d = 1; d < 1024; d <<= 1) {
    unsigned add = (t >= (unsigned)d) ? part[t - d] : 0u;
    __syncthreads();
    part[t] += add;
    __syncthreads();
  }
  unsigned base = (t == 0u) ? 0u : part[t - 1];
#pragma unroll
  for (int j = 0; j < 16; ++j) {
    unsigned pv = v[j];
    offs[t * 16 + j] = base;
    deg[t * 16 + j] = base; // deg[] becomes the build cursor
    base += pv;
  }
  if (t == 1023u) offs[16384] = base; // == E
}

// ---------------- kernel 3: counting-sort edges by row --------------------------
__global__ __launch_bounds__(256) void k_build(const unsigned* __restrict__ eidx,
                                               unsigned* __restrict__ ws) {
  __shared__ int flag32;
  if (threadIdx.x == 0) flag32 = 0;
  __syncthreads();
  unsigned e = blockIdx.x * 256u + threadIdx.x;
  if (eidx[2u * e + 1u] != 0u) flag32 = 1;
  __syncthreads();
  int row, col;
  if (flag32) {
    row = (int)eidx[e];
    col = (int)eidx[e + E_];
  } else {
    const long long* p = (const long long*)eidx;
    row = (int)p[e];
    col = (int)p[e + E_];
  }
  unsigned pos = atomicAdd(ws + DEG_OFF + (unsigned)row, 1u);
  ws[SCOL_OFF + pos] = (unsigned)col;
}

// ---------------- kernel 4: channel-split CSR gather-max (bf16) -----------------
// half = slowest grid bit, batch = blockIdx&7: per-XCD gather working set is a
// 2 MB (batch, channel-half) slice -> L2-resident (if %8 round-robin holds;
// neutral if not). Wave = 2 edges x 32 lanes (1 u32 = 2 channels per lane).
// Max trick: fmax on raw u32 (hi channel; garbage low mantissa can't flip a
// bf16-level compare) and on u<<16 (lo channel, exact).
__global__ __launch_bounds__(256) void k_aggr3(const unsigned* __restrict__ xbf,
                                               const unsigned* __restrict__ ws,
                                               unsigned* __restrict__ aggr32) {
  const unsigned bi = blockIdx.x;           // 65536 = 2 halves x 4096 rg x 8 b
  const unsigned b  = bi & 7u;
  const unsigned h  = bi >> 15;             // channel-half phase
  const unsigned rg = (bi >> 3) & 4095u;
  const unsigned row = (rg << 2) | (threadIdx.x >> 6); // wave <-> row
  const unsigned lane = threadIdx.x & 63u;
  const unsigned g  = lane >> 5;            // edge subgroup (0/1)
  const unsigned ln = lane & 31u;           // u32 slot within half
  const unsigned* offs = ws + OFFS_OFF;
  const unsigned* scol = ws + SCOL_OFF;
  const unsigned* xb = xbf + ((size_t)b << 20) + (h << 5); // rows stride 64 u32

  const unsigned j0 = offs[row], e1 = offs[row + 1];
  const bool has = (j0 < e1);
  unsigned j = j0;
  float mlo = -INFINITY, mhi = -INFINITY;
  while (j + 8u <= e1) { // 8 edges per iter, 4 per group, 4 loads in flight
    unsigned u[4];
#pragma unroll
    for (int t = 0; t < 4; ++t) {
      unsigned col = scol[j + 2u * t + g];
      u[t] = xb[(col << 6) + ln];
    }
#pragma unroll
    for (int t = 0; t < 4; ++t) {
      mlo = fmaxf(mlo, __uint_as_float(u[t] << 16));
      mhi = fmaxf(mhi, __uint_as_float(u[t]));
    }
    j += 8u;
  }
  while (j + 2u <= e1) {
    unsigned col = scol[j + g];
    unsigned u = xb[(col << 6) + ln];
    mlo = fmaxf(mlo, __uint_as_float(u << 16));
    mhi = fmaxf(mhi, __uint_as_float(u));
    j += 2u;
  }
  if (j < e1 && g == 0u) {
    unsigned u = xb[(scol[j] << 6) + ln];
    mlo = fmaxf(mlo, __uint_as_float(u << 16));
    mhi = fmaxf(mhi, __uint_as_float(u));
  }
  mlo = fmaxf(mlo, __shfl_xor(mlo, 32, 64)); // merge the two edge subgroups
  mhi = fmaxf(mhi, __shfl_xor(mhi, 32, 64));
  if (g == 0u) {
    float Mlo = has ? mlo : 0.0f;
    float Mhi = has ? __uint_as_float(__float_as_uint(mhi) & 0xFFFF0000u) : 0.0f;
    unsigned xw = xb[(row << 6) + ln];
    unsigned lo = f2bf(Mlo - __uint_as_float(xw << 16));
    unsigned hi = f2bf(Mhi - __uint_as_float(xw & 0xFFFF0000u));
    aggr32[((size_t)b << 20) + (h << 5) + (row << 6) + ln] = lo | (hi << 16);
  }
}

// ---------------- kernel 5: aggr(bf16) @ Wt(bf16) + b, exact GELU ---------------
// A-fragments read directly from global (no intra-block A reuse; the 4 unrolled
// kc loads cover full 64B lines per row). LDS = Wt only -> 4 blocks/CU.
__global__ __launch_bounds__(256, 4) void k_gemm(const unsigned short* __restrict__ aggr,
                                                 const unsigned short* __restrict__ Wt,
                                                 const float* __restrict__ bias,
                                                 float* __restrict__ out) {
  __shared__ unsigned short Wt_sm[128 * 136]; // 34816 B; stride 136 (2-way free)
  const int tid = threadIdx.x;
  const int nbase = blockIdx.x * 128; // n-tiles adjacent in dispatch: A re-read
  const int mbase = blockIdx.y * 64;  // of the same m-tile stays cache-warm

#pragma unroll
  for (int i = 0; i < 8; ++i) {
    int slot = i * 256 + tid;
    int n = slot >> 4, k8 = slot & 15;
    uint4 u = *(const uint4*)(Wt + (size_t)(nbase + n) * 128 + k8 * 8);
    *(uint4*)&Wt_sm[n * 136 + k8 * 8] = u;
  }
  __syncthreads();

  const int lane = tid & 63;
  const int wv = tid >> 6;   // wave id: rows [wv*16, wv*16+16)
  const int ln = lane & 15;
  const int q = lane >> 4;   // quad

  // A-operand: A[m = lane&15][k = quad*8 + j] -> 16B contiguous in global
  const unsigned short* arow = aggr + (size_t)(mbase + wv * 16 + ln) * 128 + q * 8;
  bf16x8 af[4];
#pragma unroll
  for (int kc = 0; kc < 4; ++kc) af[kc] = *(const bf16x8*)(arow + kc * 32);

  f32x4 acc[8];
#pragma unroll
  for (int f = 0; f < 8; ++f) acc[f] = (f32x4){0.f, 0.f, 0.f, 0.f};

#pragma unroll
  for (int kc = 0; kc < 4; ++kc) {
#pragma unroll
    for (int f = 0; f < 8; ++f) {
      // B-operand: B[k = quad*8 + j][n = lane&15] contiguous in Wt[n][k]
      bf16x8 bf = *(const bf16x8*)&Wt_sm[(f * 16 + ln) * 136 + kc * 32 + q * 8];
      acc[f] = __builtin_amdgcn_mfma_f32_16x16x32_bf16(af[kc], bf, acc[f], 0, 0, 0);
    }
  }

  // Epilogue: C/D layout col = lane&15, row = quad*4 + reg (m89-verified)
#pragma unroll
  for (int f = 0; f < 8; ++f) {
    int n = nbase + f * 16 + ln;
    float bv = bias[n];
#pragma unroll
    for (int r = 0; r < 4; ++r) {
      int m = mbase + wv * 16 + q * 4 + r;
      out[(size_t)m * 256 + n] = gelu_exact(acc[f][r] + bv);
    }
  }
}

extern "C" void kernel_launch(void* const* d_in, const int* in_sizes, int n_in,
                              void* d_out, int out_size, void* d_ws, size_t ws_size,
                              hipStream_t stream) {
  const float* x      = (const float*)d_in[0];
  const unsigned* eid = (const unsigned*)d_in[1];
  const float* W      = (const float*)d_in[2];
  const float* bia    = (const float*)d_in[3];
  float* out          = (float*)d_out;
  unsigned* ws        = (unsigned*)d_ws;

  unsigned short* Wt   = (unsigned short*)(ws + WT_OFF);
  unsigned short* aggr = (unsigned short*)(ws + AGGR_OFF);

  hipMemsetAsync(ws + DEG_OFF, 0, 16384 * sizeof(unsigned), stream);
  hipLaunchKernelGGL(k_fused1, dim3(17536),   dim3(256),  0, stream, x, eid, W, ws);
  hipLaunchKernelGGL(k_scan,   dim3(1),       dim3(1024), 0, stream, ws);
  hipLaunchKernelGGL(k_build,  dim3(1024),    dim3(256),  0, stream, eid, ws);
  hipLaunchKernelGGL(k_aggr3,  dim3(65536),   dim3(256),  0, stream,
                     ws + XBF_OFF, ws, ws + AGGR_OFF);
  hipLaunchKernelGGL(k_gemm,   dim3(2, 2048), dim3(256),  0, stream,
                     aggr, Wt, bia, out);
}